// Round 6
// baseline (1805.101 us; speedup 1.0000x reference)
//
#include <hip/hip_runtime.h>
#include <cstdint>
#include <cstddef>

typedef __bf16 bf16;

#define DINL __device__ __forceinline__

DINL float wred(float v) {
#pragma unroll
  for (int m = 32; m; m >>= 1) v += __shfl_xor(v, m, 64);
  return v;
}

// ---------- zero the fp32 accumulator (capture-safe) ----------
__global__ void k_zero(float* __restrict__ p) {
  p[blockIdx.x * 256 + threadIdx.x] = 0.f;
}

// ---------- coords: off = qf@w_off + b_off ; roi math ; softmax lw ----------
__global__ void k_coords(const float* __restrict__ qf, const float* __restrict__ roi,
                         const float* __restrict__ w_off, const float* __restrict__ b_off,
                         float* __restrict__ coords) {
  int bn = blockIdx.x;
  int t = threadIdx.x; // 0..383
  __shared__ float qs[256];
  __shared__ float offs[384];
  if (t < 256) qs[t] = qf[(size_t)bn * 256 + t];
  __syncthreads();
  float acc = b_off[t];
  for (int k = 0; k < 256; k++) acc += qs[k] * w_off[k * 384 + t];
  offs[t] = acc;
  __syncthreads();
  if (t < 128) {
    float ox = offs[t * 3 + 0], oy = offs[t * 3 + 1], oz = offs[t * 3 + 2];
    float cx = roi[bn * 4 + 0], cy = roi[bn * 4 + 1];
    float z  = roi[bn * 4 + 2], rr = roi[bn * 4 + 3];
    float sx = cx + ox * exp2f(z - 0.5f * rr);
    float sy = cy + oy * exp2f(z + 0.5f * rr);
    float lvl = z + oz;
    float e[4], mx = -1e30f;
#pragma unroll
    for (int l = 0; l < 4; l++) {
      float d = lvl - 3.0f - (float)l;
      e[l] = -d * d * 0.5f;           // TAU = 2
      mx = fmaxf(mx, e[l]);
    }
    float s = 0.f;
#pragma unroll
    for (int l = 0; l < 4; l++) { e[l] = expf(e[l] - mx); s += e[l]; }
    float inv = 1.f / s;
    float* o = coords + ((size_t)bn * 128 + t) * 6;
    o[0] = sx; o[1] = sy;
#pragma unroll
    for (int l = 0; l < 4; l++) o[2 + l] = e[l] * inv;
  }
}

// ---------- sampling: bilinear, native (B,256,H,W) fp32 layout ----------
__global__ __launch_bounds__(256) void k_sample(
    const float* __restrict__ coords,
    const float* __restrict__ x0, const float* __restrict__ x1,
    const float* __restrict__ x2, const float* __restrict__ x3,
    bf16* __restrict__ sampled) {
  const int   Wl[4] = {336, 168, 84, 42};
  const int   Hl[4] = {200, 100, 50, 25};
  const float IS[4] = {0.25f, 0.125f, 0.0625f, 0.03125f};
  const float* xs[4] = {x0, x1, x2, x3};
  int blk = blockIdx.x;          // bn*4 + g
  int bn = blk >> 2, g = blk & 3;
  int b = (bn >= 300) ? 1 : 0;
  int c = threadIdx.x & 63, pp = threadIdx.x >> 6;
  int ch = b * 256 + g * 64 + c;
#pragma unroll
  for (int p8 = 0; p8 < 8; p8++) {
    int p = p8 * 4 + pp;
    const float* cd = coords + ((size_t)bn * 128 + g * 32 + p) * 6;
    float sx = cd[0], sy = cd[1];
    float acc = 0.f;
#pragma unroll
    for (int l = 0; l < 4; l++) {
      float wl = cd[2 + l];
      int W = Wl[l], H = Hl[l];
      float xf = sx * IS[l] - 0.5f;
      float yf = sy * IS[l] - 0.5f;
      float xx0 = floorf(xf), yy0 = floorf(yf);
      float fx = xf - xx0, fy = yf - yy0;
      int xi = (int)xx0, yi = (int)yy0;
      const float* base = xs[l] + (size_t)ch * H * W;
      float v = 0.f;
      if (xi >= 0     && xi < W     && yi >= 0     && yi < H)
        v += (1.f - fx) * (1.f - fy) * base[yi * W + xi];
      if (xi + 1 >= 0 && xi + 1 < W && yi >= 0     && yi < H)
        v += fx * (1.f - fy) * base[yi * W + xi + 1];
      if (xi >= 0     && xi < W     && yi + 1 >= 0 && yi + 1 < H)
        v += (1.f - fx) * fy * base[(yi + 1) * W + xi];
      if (xi + 1 >= 0 && xi + 1 < W && yi + 1 >= 0 && yi + 1 < H)
        v += fx * fy * base[(yi + 1) * W + xi + 1];
      acc += wl * v;
    }
    sampled[((size_t)blk * 32 + p) * 64 + c] = (bf16)acc;
  }
}

// ---------- naive params GEMM: pchunk[m][a] = sum_k qf[m_off+m][k]*pg_w[k][a] + pg_b[a]
// block: 16 m-rows x 256 a-cols; thread = one column.
__global__ __launch_bounds__(256) void k_params_naive(
    const float* __restrict__ qf, const float* __restrict__ pg_w,
    const float* __restrict__ pg_b, bf16* __restrict__ pchunk,
    int m_off, int m_cnt) {
  __shared__ float qs[16][256];
  int tid = threadIdx.x;
  int a = blockIdx.x * 256 + tid;
  int m0 = blockIdx.y * 16;
#pragma unroll
  for (int j = 0; j < 16; j++) {
    int idx = tid + j * 256;          // [0, 4096)
    int rr = idx >> 8, kk = idx & 255;
    int m = m0 + rr;
    qs[rr][kk] = (m < m_cnt) ? qf[(size_t)(m_off + m) * 256 + kk] : 0.f;
  }
  __syncthreads();
  float acc[16];
#pragma unroll
  for (int r = 0; r < 16; r++) acc[r] = 0.f;
  for (int k = 0; k < 256; k++) {
    float w = pg_w[(size_t)k * 32768 + a];
#pragma unroll
    for (int r = 0; r < 16; r++) acc[r] += qs[r][k] * w;
  }
  float bv = pg_b[a];
#pragma unroll
  for (int r = 0; r < 16; r++) {
    int m = m0 + r;
    if (m < m_cnt) pchunk[(size_t)m * 32768 + a] = (bf16)(acc[r] + bv);
  }
}

// ---------- naive mixing: one block per (bn_local, g) ----------
// params slice (natural): [0,4096) = M (c*64+d), [4096,8192) = S (o*32+p)
// overwritten in place with h2 (o*64+d)
__global__ __launch_bounds__(256) void k_mix_naive(
    const bf16* __restrict__ sampled, bf16* __restrict__ params, int m_off) {
  int bnl = blockIdx.x, g = blockIdx.y;
  int tid = threadIdx.x;
  __shared__ float samp_s[2048];
  __shared__ float h1[2048];
  __shared__ float h2[8192];
  __shared__ float red[8];
  const bf16* samp = sampled + ((size_t)(m_off + bnl) * 4 + g) * 2048;
  bf16* pr = params + (size_t)bnl * 32768 + (size_t)g * 8192;

  // stage sampled (p*64+c)
#pragma unroll
  for (int j = 0; j < 8; j++) samp_s[tid + j * 256] = (float)samp[tid + j * 256];
  __syncthreads();

  // h1[p][d] = sum_c samp[p][c] * M[c][d]
#pragma unroll
  for (int j = 0; j < 8; j++) {
    int e = tid + j * 256;
    int p = e >> 6, d = e & 63;
    float s = 0.f;
    for (int c = 0; c < 64; c++) s += samp_s[p * 64 + c] * (float)pr[c * 64 + d];
    h1[e] = s;
  }
  __syncthreads();

  // LN over 2048 + relu
  {
    float s = 0.f, ss = 0.f;
#pragma unroll
    for (int j = 0; j < 8; j++) { float v = h1[tid + j * 256]; s += v; ss += v * v; }
    s = wred(s); ss = wred(ss);
    int w = tid >> 6;
    if ((tid & 63) == 0) { red[w] = s; red[4 + w] = ss; }
    __syncthreads();
    s = red[0] + red[1] + red[2] + red[3];
    ss = red[4] + red[5] + red[6] + red[7];
    float mean = s * (1.f / 2048.f);
    float var = ss * (1.f / 2048.f) - mean * mean;
    float rs = rsqrtf(fmaxf(var, 0.f) + 1e-5f);
    __syncthreads();   // red[] reused below
#pragma unroll
    for (int j = 0; j < 8; j++) {
      int e = tid + j * 256;
      float v = (h1[e] - mean) * rs;
      h1[e] = v > 0.f ? v : 0.f;
    }
  }
  __syncthreads();

  // h2[o][d] = sum_p S[o][p] * h1[p][d]
#pragma unroll
  for (int j = 0; j < 32; j++) {
    int e = tid + j * 256;
    int o = e >> 6, d = e & 63;
    float s = 0.f;
    for (int p = 0; p < 32; p++) s += (float)pr[4096 + o * 32 + p] * h1[p * 64 + d];
    h2[e] = s;
  }
  __syncthreads();

  // LN over 8192 + relu, write back as h2 flat (o*64+d)
  {
    float s = 0.f, ss = 0.f;
#pragma unroll
    for (int j = 0; j < 32; j++) { float v = h2[tid + j * 256]; s += v; ss += v * v; }
    s = wred(s); ss = wred(ss);
    int w = tid >> 6;
    if ((tid & 63) == 0) { red[w] = s; red[4 + w] = ss; }
    __syncthreads();
    s = red[0] + red[1] + red[2] + red[3];
    ss = red[4] + red[5] + red[6] + red[7];
    float mean = s * (1.f / 8192.f);
    float var = ss * (1.f / 8192.f) - mean * mean;
    float rs = rsqrtf(fmaxf(var, 0.f) + 1e-5f);
    __syncthreads();
#pragma unroll
    for (int j = 0; j < 32; j++) {
      int e = tid + j * 256;
      float v = (h2[e] - mean) * rs;
      v = v > 0.f ? v : 0.f;
      pr[e] = (bf16)v;   // e = o*64+d exactly
    }
  }
}

// ---------- naive final GEMM (k-split + atomics) ----------
// facc[m_off+m][n] += sum_{k in tile} h2[m][k] * op_w[k][n]
__global__ __launch_bounds__(256) void k_final_naive(
    const bf16* __restrict__ pchunk, const float* __restrict__ op_w,
    float* __restrict__ facc, int m_off, int m_cnt) {
  __shared__ bf16 hs[16][2048];   // 64 KiB
  int tid = threadIdx.x;
  int k0 = blockIdx.x * 2048;
  int m0 = blockIdx.y * 16;
  int n = tid;
#pragma unroll
  for (int j = 0; j < 128; j++) {
    int idx = tid + j * 256;            // [0, 32768)
    int r = idx >> 11, kk = idx & 2047;
    int m = m0 + r;
    hs[r][kk] = (m < m_cnt) ? pchunk[(size_t)m * 32768 + k0 + kk] : (bf16)0.f;
  }
  __syncthreads();
  float acc[16];
#pragma unroll
  for (int r = 0; r < 16; r++) acc[r] = 0.f;
  for (int kk = 0; kk < 2048; kk++) {
    float w = op_w[(size_t)(k0 + kk) * 256 + n];
#pragma unroll
    for (int r = 0; r < 16; r++) acc[r] += (float)hs[r][kk] * w;
  }
#pragma unroll
  for (int r = 0; r < 16; r++) {
    int m = m0 + r;
    if (m < m_cnt) atomicAdd(&facc[(size_t)(m_off + m) * 256 + n], acc[r]);
  }
}

// ---------- final LN epilogue ----------
__global__ void k_ln(const float* __restrict__ accbuf, const float* __restrict__ qf,
                     const float* __restrict__ opb, const float* __restrict__ lng,
                     const float* __restrict__ lnb, float* __restrict__ out) {
  int bn = blockIdx.x, t = threadIdx.x;
  float v = accbuf[bn * 256 + t] + qf[(size_t)bn * 256 + t] + opb[t];
  __shared__ float red[8];
  float s = wred(v), ss = wred(v * v);
  int w = t >> 6;
  if ((t & 63) == 0) { red[w] = s; red[4 + w] = ss; }
  __syncthreads();
  s = red[0] + red[1] + red[2] + red[3];
  ss = red[4] + red[5] + red[6] + red[7];
  float mean = s * (1.f / 256.f);
  float var = ss * (1.f / 256.f) - mean * mean;
  float y = (v - mean) * rsqrtf(fmaxf(var, 0.f) + 1e-5f);
  out[(size_t)bn * 256 + t] = y * lng[t] + lnb[t];
}

// ---------------- launcher ----------------
// ALL INPUTS AND OUTPUT ARE FLOAT32 (reference dtype). Internal buffers:
//   coords  @ 0           (1,843,200 B, fp32)
//   sampled @ 1,843,200   (9,830,400 B, bf16)
//   facc    @ 11,673,600  (614,400 B, fp32)
//   pchunk  @ 12,288,000  (19,660,800 B, bf16)  // params for 300 queries/chunk
// total 31,948,800 B (proven to fit ws_size in R4).
extern "C" void kernel_launch(void* const* d_in, const int* in_sizes, int n_in,
                              void* d_out, int out_size, void* d_ws, size_t ws_size,
                              hipStream_t stream) {
  const float* x0    = (const float*)d_in[0];
  const float* x1    = (const float*)d_in[1];
  const float* x2    = (const float*)d_in[2];
  const float* x3    = (const float*)d_in[3];
  const float* qf    = (const float*)d_in[4];
  const float* roi   = (const float*)d_in[5];
  const float* w_off = (const float*)d_in[6];
  const float* b_off = (const float*)d_in[7];
  const float* pg_w  = (const float*)d_in[8];
  const float* pg_b  = (const float*)d_in[9];
  const float* op_w  = (const float*)d_in[10];
  const float* op_b  = (const float*)d_in[11];
  const float* ln_g  = (const float*)d_in[12];
  const float* ln_b  = (const float*)d_in[13];
  float* out = (float*)d_out;

  const size_t NEEDED = 31948800ull;
  if (ws_size < NEEDED) return;

  char* ws = (char*)d_ws;
  float* coords  = (float*)(ws + 0);
  bf16*  sampled = (bf16*)(ws + 1843200);
  float* facc    = (float*)(ws + 11673600);
  bf16*  pchunk  = (bf16*)(ws + 12288000);

  k_zero<<<600, 256, 0, stream>>>(facc);
  k_coords<<<600, 384, 0, stream>>>(qf, roi, w_off, b_off, coords);
  k_sample<<<2400, 256, 0, stream>>>(coords, x0, x1, x2, x3, sampled);

  for (int chunk = 0; chunk < 2; chunk++) {
    int m_off = chunk * 300, m_cnt = 300;
    k_params_naive<<<dim3(128, 19), 256, 0, stream>>>(qf, pg_w, pg_b, pchunk, m_off, m_cnt);
    k_mix_naive<<<dim3(300, 4), 256, 0, stream>>>(sampled, pchunk, m_off);
    k_final_naive<<<dim3(16, 19), 256, 0, stream>>>(pchunk, op_w, facc, m_off, m_cnt);
  }

  k_ln<<<600, 256, 0, stream>>>(facc, qf, op_b, ln_g, ln_b, out);
}